// Round 1
// baseline (426.255 us; speedup 1.0000x reference)
//
#include <hip/hip_runtime.h>
#include <hip/hip_bf16.h>

// ModulatedConv (StyleGAN2 conv_transpose2d stride=2, K=3) on gfx950.
// out[b,o,y,x] = inv[b,o] * sum_{i,ky,kx} (scale_w*weight[o,i,ky,kx]) * (s[b,i]*x[b,i,h,w])
// Round 3: 2-phase pipelined main loop (X double-buffered in LDS, staged for
// kc+1 while computing kc; W loaded straight to registers, no LDS round-trip),
// XCD-chunked grid swizzle (each XCD owns 2 batch slices, y-major, px fastest
// for output-line write merge). LDS 32KB.

typedef __attribute__((ext_vector_type(8))) short short8;
typedef __attribute__((ext_vector_type(4))) float floatx4;

#define CIN   512
#define COUT  512
#define HH    32
#define OW    65
#define NSITE 1089     // 33*33 sites (u,v); out y=2u+py, x=2v+px

__device__ __forceinline__ void gload16(const void* g, void* l) {
    __builtin_amdgcn_global_load_lds(
        (const __attribute__((address_space(1))) void*)g,
        (__attribute__((address_space(3))) void*)l, 16, 0, 0);
}

// ---- prep kernels ------------------------------------------------------

// s[b,i] = (1/16) * dot(w[b,:], lin_w[i,:]) + lin_b[i]
__global__ void k_s(const float* __restrict__ w, const float* __restrict__ lin_w,
                    const float* __restrict__ lin_b, float* __restrict__ s)
{
    int i = blockIdx.x * 256 + threadIdx.x;
    int b = blockIdx.y;
    const float* wr = w + b * 512;
    const float* lr = lin_w + (size_t)i * 512;
    float acc = 0.f;
    for (int d = 0; d < 512; d += 4) {
        float4 a = *(const float4*)(wr + d);
        float4 c = *(const float4*)(lr + d);
        acc += a.x*c.x + a.y*c.y + a.z*c.z + a.w*c.w;
    }
    s[b * 512 + i] = acc * 0.0625f + lin_b[i];
}

// fused: q[o,i] = sum_kk weight[o,i,kk]^2 ; wT[t][o][i] = bf16(weight[o,i,t]/48)
__global__ void k_wq(const float* __restrict__ weight,
                     __hip_bfloat16* __restrict__ wT, float* __restrict__ q)
{
    int idx = blockIdx.x * 256 + threadIdx.x;   // o*512+i, < 262144
    const float* p = weight + (size_t)idx * 9;
    float v[9], acc = 0.f;
#pragma unroll
    for (int j = 0; j < 9; ++j) { v[j] = p[j]; acc += v[j] * v[j]; }
    q[idx] = acc;
#pragma unroll
    for (int t = 0; t < 9; ++t)
        wT[t * 262144 + idx] = __float2bfloat16(v[t] * (1.0f / 48.0f));
}

// inv[b,o] = 1/sqrt((1/2304) * sum_i s[b,i]^2 q[o,i] + 1e-8)
__global__ void k_inv(const float* __restrict__ s, const float* __restrict__ q,
                      float* __restrict__ inv)
{
    int idx = blockIdx.x * 256 + threadIdx.x;   // b*512+o
    int b = idx >> 9;
    int o = idx & 511;
    const float* sp = s + b * 512;
    const float* qp = q + (size_t)o * 512;
    float acc = 0.f;
    for (int i = 0; i < 512; i += 4) {
        float4 sv = *(const float4*)(sp + i);
        float4 qv = *(const float4*)(qp + i);
        acc += sv.x*sv.x*qv.x + sv.y*sv.y*qv.y + sv.z*sv.z*qv.z + sv.w*sv.w*qv.w;
    }
    inv[idx] = 1.0f / sqrtf(acc * (1.0f / 2304.0f) + 1e-8f);
}

// zero the halo border of xmp [16][34][34][512]
__global__ void k_zero(__hip_bfloat16* __restrict__ xmp)
{
    int idx = blockIdx.x * 256 + threadIdx.x;   // < 16*132*64
    int kc = idx & 63;
    int j  = (idx >> 6) % 132;
    int b  = (idx >> 6) / 132;
    int r, c;
    if (j < 34)       { r = 0;          c = j; }
    else if (j < 68)  { r = 33;         c = j - 34; }
    else if (j < 100) { r = j - 68 + 1; c = 0; }
    else              { r = j - 100 + 1; c = 33; }
    uint4 z = {0u, 0u, 0u, 0u};
    *(uint4*)(xmp + (((size_t)b * 34 + r) * 34 + c) * 512 + kc * 8) = z;
}

// xmp[b][h+1][w+1][i] = bf16(s[b,i] * x[b,i,h,w])   (channel-minor, padded halo)
__global__ void k_xprep(const float* __restrict__ x, const float* __restrict__ s,
                        __hip_bfloat16* __restrict__ xmp)
{
    __shared__ float tile[32][33];
    int i0 = blockIdx.x * 32;
    int h  = blockIdx.y;
    int b  = blockIdx.z;
    int tw = threadIdx.x & 31;
    int ti = threadIdx.x >> 5;
#pragma unroll
    for (int r = 0; r < 4; ++r) {
        int il = ti + r * 8;
        int i  = i0 + il;
        tile[il][tw] = x[(((size_t)b * 512 + i) * 32 + h) * 32 + tw] * s[b * 512 + i];
    }
    __syncthreads();
#pragma unroll
    for (int r = 0; r < 4; ++r) {
        int wc = ti + r * 8;
        xmp[(((size_t)b * 34 + h + 1) * 34 + (wc + 1)) * 512 + i0 + tw] =
            __float2bfloat16(tile[tw][wc]);
    }
}

// ---- main conv kernel --------------------------------------------------
// Logical tile: M=128 o x N=128 sites, K-chunks of 32, 4 waves (wm x wn).
// X tile double-buffered in LDS (2 x 16KB), staged via global_load_lds for
// chunk kc+1 while chunk kc computes; one __syncthreads per chunk (its
// vmcnt(0) drain lands AFTER the compute -> latency hidden). W fragments are
// loaded straight from global to registers (L2-resident after the grid
// swizzle); taps 0..1 preloaded BEFORE the stage is issued so their vmcnt
// waits never force the stage to drain; NT=4 prefetches taps 2..3 during
// taps 0..1 compute (stage drains at 50% of compute, >= L2 latency).
// XOR k-slot swizzle on Xl kept from round 2 (2-way banks only).

template <int PHASE>
__device__ __forceinline__ void conv_body(
    const __hip_bfloat16* __restrict__ wT,
    const __hip_bfloat16* __restrict__ xmp,
    const float* __restrict__ inv,
    float* __restrict__ out,
    short* Xl, const int site_tile, const int o_tile, const int b)
{
    constexpr int NT = (PHASE == 0) ? 4 : (PHASE == 3) ? 1 : 2;
    constexpr int TAPT[4][4] = {{0,2,6,8},{1,7,0,0},{3,5,0,0},{4,0,0,0}};
    constexpr int TSLT[4][4] = {{35,34,1,0},{35,1,0,0},{35,34,0,0},{35,0,0,0}};

    const int tid  = threadIdx.x;
    const int lane = tid & 63;
    const int wv   = tid >> 6;
    const int wm   = wv & 1;
    const int wn   = wv >> 1;
    const int quad = lane >> 4;
    const int c16  = lane & 15;

    const int s0     = site_tile * 128;
    const int u_base = s0 / 33;
    const int o_base = o_tile * 128;

    // A fragment global element offsets (within one tap slice, before k0)
    int aoffg[4];
#pragma unroll
    for (int a = 0; a < 4; ++a)
        aoffg[a] = (wm * 64 + a * 16 + c16) * CIN + quad * 8;

    const __hip_bfloat16* wtap[NT];
#pragma unroll
    for (int t = 0; t < NT; ++t)
        wtap[t] = wT + ((size_t)(TAPT[PHASE][t] * COUT + o_base)) * CIN;

    // B fragment LDS offsets per (tap, f), swizzled
    int boff[NT][4];
#pragma unroll
    for (int f = 0; f < 4; ++f) {
        int site = s0 + wn * 64 + f * 16 + c16;
        int u = site / 33;
        int v = site - u * 33;
        int sb = (u - u_base) * 34 + v;
#pragma unroll
        for (int t = 0; t < NT; ++t) {
            int sl = sb + TSLT[PHASE][t];
            boff[t][f] = sl * 32 + ((quad ^ ((sl >> 1) & 3)) << 3);
        }
    }
    // X staging global pointers (hoisted; add k per chunk)
    const __hip_bfloat16* xg[4];
#pragma unroll
    for (int it = 0; it < 4; ++it) {
        int ch   = it * 256 + tid;
        int slot = ch >> 2;
        int kg   = (ch & 3) ^ ((slot >> 1) & 3);
        int r    = slot / 34;
        int c    = slot - r * 34;
        int h1   = u_base + r;                  // padded xmp row (= h_x + 1)
        xg[it] = (slot < 204 && h1 <= 33)
                   ? xmp + (((size_t)b * 34 + h1) * 34 + c) * 512 + kg * 8
                   : xmp;                       // dummy; those slots never read
    }
    // wave-uniform LDS staging base (shorts)
    const int wub = (tid & 192) * 8;

    floatx4 acc[4][4];
#pragma unroll
    for (int a = 0; a < 4; ++a)
#pragma unroll
        for (int f = 0; f < 4; ++f)
            acc[a][f] = (floatx4){0.f, 0.f, 0.f, 0.f};

    // prologue: stage chunk 0 into buffer 0
#pragma unroll
    for (int it = 0; it < 4; ++it)
        gload16(xg[it], &Xl[it * 2048 + wub]);
    __syncthreads();

    int cur = 0;
    for (int kc = 0; kc < 16; ++kc) {
        const int k0 = kc * 32;

        // preload A for taps 0..min(NT,2)-1 BEFORE issuing the stage, so
        // waiting on them cannot force the staged loads to complete.
        short8 Areg[2][4];
        constexpr int NPRE = (NT < 2) ? NT : 2;
#pragma unroll
        for (int t = 0; t < NPRE; ++t)
#pragma unroll
            for (int a = 0; a < 4; ++a)
                Areg[t][a] = *(const short8*)(wtap[t] + aoffg[a] + k0);

        if (kc < 15) {
            const int nb = (cur ^ 1) * 8192;
#pragma unroll
            for (int it = 0; it < 4; ++it)
                gload16(xg[it] + k0 + 32, &Xl[nb + it * 2048 + wub]);
        }

        const int cb = cur * 8192;
#pragma unroll
        for (int t = 0; t < NT; ++t) {
#pragma unroll
            for (int f = 0; f < 4; ++f) {
                short8 Bf = *(const short8*)(&Xl[cb + boff[t][f]]);
                acc[0][f] = __builtin_amdgcn_mfma_f32_16x16x32_bf16(Areg[t & 1][0], Bf, acc[0][f], 0, 0, 0);
                acc[1][f] = __builtin_amdgcn_mfma_f32_16x16x32_bf16(Areg[t & 1][1], Bf, acc[1][f], 0, 0, 0);
                acc[2][f] = __builtin_amdgcn_mfma_f32_16x16x32_bf16(Areg[t & 1][2], Bf, acc[2][f], 0, 0, 0);
                acc[3][f] = __builtin_amdgcn_mfma_f32_16x16x32_bf16(Areg[t & 1][3], Bf, acc[3][f], 0, 0, 0);
            }
            if (t + 2 < NT)       // NT==4 only: prefetch taps 2,3 mid-compute
#pragma unroll
                for (int a = 0; a < 4; ++a)
                    Areg[t & 1][a] = *(const short8*)(wtap[t + 2] + aoffg[a] + k0);
        }
        __syncthreads();          // drains stage(kc+1) AFTER compute; barrier
        cur ^= 1;
    }

    // epilogue: D col(lane&15)->site, row(quad*4+reg)->o; scale by inv[b,o]
    constexpr int py = PHASE >> 1, px = PHASE & 1;
#pragma unroll
    for (int a = 0; a < 4; ++a) {
        const int ob = o_base + wm * 64 + a * 16 + quad * 4;
        float iv[4];
#pragma unroll
        for (int r = 0; r < 4; ++r) iv[r] = inv[b * COUT + ob + r];
#pragma unroll
        for (int f = 0; f < 4; ++f) {
            int site = s0 + wn * 64 + f * 16 + c16;
            if (site < NSITE) {
                int u = site / 33;
                int v = site - u * 33;
                int y  = 2 * u + py;
                int xq = 2 * v + px;
                if (y < OW && xq < OW) {
#pragma unroll
                    for (int r = 0; r < 4; ++r)
                        out[(((size_t)b * COUT + ob + r) * OW + y) * OW + xq] =
                            acc[a][f][r] * iv[r];
                }
            }
        }
    }
}

__global__ __launch_bounds__(256, 3)
void conv_main(const __hip_bfloat16* __restrict__ wT,
               const __hip_bfloat16* __restrict__ xmp,
               const float* __restrict__ inv,
               float* __restrict__ out)
{
    __shared__ short Xl[16384];   // 32 KB: 2 x (256 slots x 32 k)

    // XCD-chunked swizzle: hw linear id n -> XCD ~ n%8. Give XCD j the
    // contiguous logical range [j*288,(j+1)*288): exactly 2 batch slices,
    // y-major (site fastest). Working set per XCD ~ xmp[b] 1.18MB + one
    // W slice <=0.5MB -> fits 4MB L2. y ordered px-fastest so the px=0/1
    // blocks writing the same output lines run ~9 blocks apart (L2 merge).
    const int n   = blockIdx.x + 9 * blockIdx.y + 144 * blockIdx.z;
    const int lg  = (n & 7) * 288 + (n >> 3);
    const int b   = lg / 144;
    const int rem = lg - b * 144;
    const int y    = rem / 9;
    const int site = rem - y * 9;
    const int px = y & 1, py = (y >> 1) & 1, o_tile = y >> 2;
    const int phase = py * 2 + px;

    switch (phase) {
        case 0: conv_body<0>(wT, xmp, inv, out, Xl, site, o_tile, b); break;
        case 1: conv_body<1>(wT, xmp, inv, out, Xl, site, o_tile, b); break;
        case 2: conv_body<2>(wT, xmp, inv, out, Xl, site, o_tile, b); break;
        default: conv_body<3>(wT, xmp, inv, out, Xl, site, o_tile, b); break;
    }
}

// ---- launcher ----------------------------------------------------------
extern "C" void kernel_launch(void* const* d_in, const int* in_sizes, int n_in,
                              void* d_out, int out_size, void* d_ws, size_t ws_size,
                              hipStream_t stream)
{
    const float* x      = (const float*)d_in[0];   // (16,512,32,32)
    const float* w      = (const float*)d_in[1];   // (16,512)
    const float* weight = (const float*)d_in[2];   // (1,512,512,3,3)
    const float* lin_w  = (const float*)d_in[3];   // (512,512)
    const float* lin_b  = (const float*)d_in[4];   // (512,)
    float* out = (float*)d_out;                    // (16,512,65,65)

    char* ws = (char*)d_ws;
    float* s_buf   = (float*)(ws);                         //   32 KB
    float* inv_buf = (float*)(ws + 32768);                 //   32 KB
    float* q_buf   = (float*)(ws + 65536);                 //    1 MB
    __hip_bfloat16* wT  = (__hip_bfloat16*)(ws + 1114112); // 4.72 MB [9][512][512]
    __hip_bfloat16* xmp = (__hip_bfloat16*)(ws + 5832704); // 18.9 MB [16][34][34][512]

    k_s    <<<dim3(2, 16),      256, 0, stream>>>(w, lin_w, lin_b, s_buf);
    k_wq   <<<1024,             256, 0, stream>>>(weight, wT, q_buf);
    k_zero <<<528,              256, 0, stream>>>(xmp);
    k_inv  <<<32,               256, 0, stream>>>(s_buf, q_buf, inv_buf);
    k_xprep<<<dim3(16, 32, 16), 256, 0, stream>>>(x, s_buf, xmp);
    conv_main<<<dim3(9, 16, 16), 256, 0, stream>>>(wT, xmp, inv_buf, out);
}